// Round 11
// baseline (106.185 us; speedup 1.0000x reference)
//
#include <hip/hip_runtime.h>
#include <hip/hip_bf16.h>

#define B_ 4
#define S_ 4096
#define D_ 1024
#define H_ 128

typedef _Float16 half8 __attribute__((ext_vector_type(8)));
typedef _Float16 half4v __attribute__((ext_vector_type(4)));
typedef float float4v __attribute__((ext_vector_type(4)));

// Fragment-major layouts (all loads in hot kernels are base + lane*16B bursts):
//   WTz[((w*32 + K32)*8 + ntg)*512 + lane*8 + e] = W_w[K32*32 + (lane>>4)*8 + e][ntg*16 + (lane&15)]
//   Kz[(b*128+tt)*4096 + (k2*2+c)*512 + lane*8 + e]
//     = K[b][tt*32 + permbase(lane&15) + 4c][k2*32 + (lane>>4)*8 + e]
//   Vz[(b*128+tt)*4096 + hc*512 + lane*8 + e]
//     = V[b][tt*32 + (lane>>4)*8 + e][hc*16 + (lane&15)]
// (permbase(l) = ((l>>2)<<3)+(l&3))

// ------------- kernel 1: W[k][n] fp32 -> WTz fragment-major f16 -------------
__global__ __launch_bounds__(256) void k_cvt_w(const float* __restrict__ Wq,
                                               const float* __restrict__ Wk,
                                               const float* __restrict__ Wv,
                                               _Float16* __restrict__ WTz) {
    const float* W = blockIdx.y == 0 ? Wq : (blockIdx.y == 1 ? Wk : Wv);
    const int idx  = blockIdx.x * 256 + threadIdx.x;   // 0..16383 (grid.x = 64)
    const int lane = idx & 63, ntg = (idx >> 6) & 7, K32 = idx >> 9;
    const int lo = lane & 15, hi = lane >> 4;
    half8 v;
#pragma unroll
    for (int e = 0; e < 8; ++e)
        v[e] = (_Float16)W[(K32 * 32 + hi * 8 + e) * H_ + ntg * 16 + lo];
    *(half8*)(WTz + (size_t)(((int)blockIdx.y * 32 + K32) * 8 + ntg) * 512 + lane * 8) = v;
}

// ------------- kernel 2: QKV projection GEMM (R11: barrier-free loop) -------
// No LDS, no __syncthreads in the K-loop -> no compiler vmcnt(0) drains (the
// R9/R10 ~2 TB/s duty-cycle cap).  Each wave owns a 64x64 output tile: A-frags
// straight from X (16x128B runs), B-frags as 1KB bursts from WTz.  4 waves =
// 128x128 block tile; bid = w*128+panel -> all 3 w-blocks of a panel on one
// XCD (X HBM-fetched once).  Epilogue: LDS transpose -> burst stores (Q row-
// major; K/V fragment-major).  Q pre-scaled by (1/sqrt(H))*log2(e).
__global__ __launch_bounds__(256, 2) void k_proj(const float* __restrict__ X,
                                                 const _Float16* __restrict__ WTz,
                                                 const float* __restrict__ bq,
                                                 const float* __restrict__ bk,
                                                 const float* __restrict__ bv,
                                                 _Float16* __restrict__ Qf,
                                                 _Float16* __restrict__ Kz,
                                                 _Float16* __restrict__ Vz) {
    __shared__ _Float16 Ct[128 * 136];             // 34.8 KB transpose tile

    const int t     = threadIdx.x;
    const int bid   = blockIdx.x;
    const int w     = bid >> 7;                    // 0=q 1=k 2=v
    const int panel = bid & 127;
    const int m0    = panel * 128;
    const int lane  = t & 63, wid = t >> 6;
    const int lo    = lane & 15, hi = lane >> 4;
    const int wr    = wid >> 1, wc = wid & 1;

    const float*    Xw = X + (size_t)(m0 + wr * 64 + lo) * D_ + hi * 8;
    const _Float16* Bw = WTz + (size_t)(w * 32 * 8 + wc * 4) * 512 + lane * 8;

    float4v acc[4][4];
#pragma unroll
    for (int mt = 0; mt < 4; ++mt)
#pragma unroll
        for (int nt = 0; nt < 4; ++nt) acc[mt][nt] = {0.f, 0.f, 0.f, 0.f};

#pragma unroll 4
    for (int K32 = 0; K32 < 32; ++K32) {
        half8 bf[4];
#pragma unroll
        for (int nt = 0; nt < 4; ++nt)
            bf[nt] = *(const half8*)(Bw + (size_t)(K32 * 8 + nt) * 512);
        half8 af[4];
#pragma unroll
        for (int mt = 0; mt < 4; ++mt) {
            const float* xp = Xw + (size_t)mt * 16 * D_ + K32 * 32;
            float4v x0 = *(const float4v*)(xp);
            float4v x1 = *(const float4v*)(xp + 4);
            half8 h;
            h[0]=(_Float16)x0[0]; h[1]=(_Float16)x0[1]; h[2]=(_Float16)x0[2]; h[3]=(_Float16)x0[3];
            h[4]=(_Float16)x1[0]; h[5]=(_Float16)x1[1]; h[6]=(_Float16)x1[2]; h[7]=(_Float16)x1[3];
            af[mt] = h;
        }
#pragma unroll
        for (int mt = 0; mt < 4; ++mt)
#pragma unroll
            for (int nt = 0; nt < 4; ++nt)
                acc[mt][nt] = __builtin_amdgcn_mfma_f32_16x16x32_f16(
                    af[mt], bf[nt], acc[mt][nt], 0, 0, 0);
    }

    // ---- epilogue: acc (+bias, *scale) -> Ct[128][136] -> burst stores ----
    const float* bias = (w == 0) ? bq : ((w == 1) ? bk : bv);
    const float scale = (w == 0) ? (0.08838834764831845f * 1.4426950408889634f) : 1.0f;
#pragma unroll
    for (int mt = 0; mt < 4; ++mt)
#pragma unroll
        for (int nt = 0; nt < 4; ++nt) {
            const int col   = wc * 64 + nt * 16 + lo;
            const float bn  = bias[col];
            const int rbase = wr * 64 + mt * 16 + 4 * hi;
#pragma unroll
            for (int j = 0; j < 4; ++j)
                Ct[(rbase + j) * 136 + col] = (_Float16)((acc[mt][nt][j] + bn) * scale);
        }
    __syncthreads();

    const int bb  = m0 >> 12;                      // batch
    const int tt0 = (m0 & (S_ - 1)) >> 5;          // first 32-row KV tile (4/block)

    if (w == 0) {                                  // Q: row-major bursts
        const int r = t >> 1, c0 = (t & 1) * 64;
        _Float16* dst = Qf + (size_t)(m0 + r) * H_ + c0;
        const _Float16* srcp = &Ct[r * 136 + c0];
#pragma unroll
        for (int cc = 0; cc < 8; ++cc)
            *(half8*)(dst + cc * 8) = *(const half8*)(srcp + cc * 8);
    } else if (w == 1) {                           // K: fragment-major bursts
        const int rowp = ((lo >> 2) << 3) + (lo & 3);
#pragma unroll
        for (int q = 0; q < 8; ++q) {
            const int fid = wid * 8 + q;           // 32 frags: 4 tiles x 4 k2 x 2 c
            const int ft = fid >> 3, k2 = (fid >> 1) & 3, c = fid & 1;
            const int row = ft * 32 + rowp + 4 * c;
            half8 v = *(const half8*)(&Ct[row * 136 + k2 * 32 + hi * 8]);
            *(half8*)(Kz + (size_t)(bb * 128 + tt0 + ft) * 4096 +
                      (k2 * 2 + c) * 512 + lane * 8) = v;
        }
    } else {                                       // V: transposed fragment-major
#pragma unroll
        for (int q = 0; q < 8; ++q) {
            const int fid = wid * 8 + q;           // 32 frags: 4 tiles x 8 hc
            const int ft = fid >> 3, hc = fid & 7;
            half8 v;
#pragma unroll
            for (int e = 0; e < 8; ++e)
                v[e] = Ct[(ft * 32 + hi * 8 + e) * 136 + hc * 16 + lo];
            *(half8*)(Vz + (size_t)(bb * 128 + tt0 + ft) * 4096 +
                      hc * 512 + lane * 8) = v;
        }
    }
}

// ---------------- kernel 3: causal flash attention (UNCHANGED from R8) ----
__global__ __launch_bounds__(512, 2) void k_attn(const _Float16* __restrict__ Qf,
                                                 const _Float16* __restrict__ Kz,
                                                 const _Float16* __restrict__ Vz,
                                                 float* __restrict__ Out) {
    __shared__ float    sm_l[8][32];
    __shared__ _Float16 sm_o[8][32][136];   // [wave][q][h], pad 128->136

    const int t    = threadIdx.x;
    const int lane = t & 63, wid = t >> 6;
    const int lo = lane & 15, hi = lane >> 4;

    const int i   = blockIdx.x;            // 0..511
    const int b   = (i >> 1) & 3;          // batch -> XCD pair {2b, 2b+1}
    const int qtr = ((i >> 3) << 1) | (i & 1);          // 0..127
    const int qt  = (qtr < 64) ? qtr : (191 - qtr);     // zigzag: i & i+256 complement
    const int q0  = qt << 5;               // 32 queries: q0..q0+31

    const _Float16* Qb = Qf + (size_t)b * (S_ * H_);
    const _Float16* Kb = Kz + (size_t)b * 524288;   // 128 tiles * 4096
    const _Float16* Vb = Vz + (size_t)b * 524288;

    half8 qfa[4], qfb[4];
#pragma unroll
    for (int kk = 0; kk < 4; ++kk) {
        qfa[kk] = *(const half8*)(Qb + (size_t)(q0 + lo) * H_ + kk * 32 + hi * 8);
        qfb[kk] = *(const half8*)(Qb + (size_t)(q0 + 16 + lo) * H_ + kk * 32 + hi * 8);
    }

    float4v oa[8], ob[8];
#pragma unroll
    for (int hc = 0; hc < 8; ++hc) { oa[hc] = {0.f,0.f,0.f,0.f}; ob[hc] = {0.f,0.f,0.f,0.f}; }
    float la = 0.f, lb = 0.f;   // LANE-LOCAL partial row-sums (reduced after loop)

    const int lane8 = lane * 8;
    const int ntiles = qt + 1;             // keys 0..q0+31, 32/tile

    // prime the K double-buffer with this wave's first tile
    half8 kc0[4], kc1[4];
    if (wid < ntiles) {
        const _Float16* Kt = Kb + (size_t)wid * 4096 + lane8;
#pragma unroll
        for (int kk = 0; kk < 4; ++kk) {
            kc0[kk] = *(const half8*)(Kt + (kk * 2    ) * 512);
            kc1[kk] = *(const half8*)(Kt + (kk * 2 + 1) * 512);
        }
    }

    for (int tt = wid; tt < ntiles; tt += 8) {
        // ---- V loads issued first: latency hides under QK + exp ----
        const _Float16* Vt = Vb + (size_t)tt * 4096 + lane8;
        half8 vf[8];
#pragma unroll
        for (int hc = 0; hc < 8; ++hc)
            vf[hc] = *(const half8*)(Vt + hc * 512);
        // ---- prefetch next K tile (clamped re-load of current on last iter) ----
        const int tn = (tt + 8 < ntiles) ? (tt + 8) : tt;
        half8 kn0[4], kn1[4];
        {
            const _Float16* Ktn = Kb + (size_t)tn * 4096 + lane8;
#pragma unroll
            for (int kk = 0; kk < 4; ++kk) {
                kn0[kk] = *(const half8*)(Ktn + (kk * 2    ) * 512);
                kn1[kk] = *(const half8*)(Ktn + (kk * 2 + 1) * 512);
            }
        }
        // ---- QK^T on the current (already-resident) K fragments ----
        float4v s0a = {0.f,0.f,0.f,0.f}, s1a = {0.f,0.f,0.f,0.f};
        float4v s0b = {0.f,0.f,0.f,0.f}, s1b = {0.f,0.f,0.f,0.f};
#pragma unroll
        for (int kk = 0; kk < 4; ++kk) {
            s0a = __builtin_amdgcn_mfma_f32_16x16x32_f16(kc0[kk], qfa[kk], s0a, 0, 0, 0);
            s0b = __builtin_amdgcn_mfma_f32_16x16x32_f16(kc0[kk], qfb[kk], s0b, 0, 0, 0);
            s1a = __builtin_amdgcn_mfma_f32_16x16x32_f16(kc1[kk], qfa[kk], s1a, 0, 0, 0);
            s1b = __builtin_amdgcn_mfma_f32_16x16x32_f16(kc1[kk], qfb[kk], s1b, 0, 0, 0);
        }
        // s0x[j] = S[q][k0+8hi+j], s1x[j] = S[q][k0+8hi+4+j]
        if (tt == qt) {   // diagonal tile: only place masking is needed
#pragma unroll
            for (int j = 0; j < 4; ++j) {
                const int c0 = 8 * hi + j, c1 = 8 * hi + 4 + j;
                if (c0 > lo)      s0a[j] = -INFINITY;
                if (c1 > lo)      s1a[j] = -INFINITY;
                if (c0 > 16 + lo) s0b[j] = -INFINITY;
                if (c1 > 16 + lo) s1b[j] = -INFINITY;
            }
        }
        // ---- no-max softmax, exp2 direct (exp2(-inf) = 0 handles masks) ----
        float pa0 = __builtin_amdgcn_exp2f(s0a[0]), pa1 = __builtin_amdgcn_exp2f(s0a[1]);
        float pa2 = __builtin_amdgcn_exp2f(s0a[2]), pa3 = __builtin_amdgcn_exp2f(s0a[3]);
        float pa4 = __builtin_amdgcn_exp2f(s1a[0]), pa5 = __builtin_amdgcn_exp2f(s1a[1]);
        float pa6 = __builtin_amdgcn_exp2f(s1a[2]), pa7 = __builtin_amdgcn_exp2f(s1a[3]);
        float pb0 = __builtin_amdgcn_exp2f(s0b[0]), pb1 = __builtin_amdgcn_exp2f(s0b[1]);
        float pb2 = __builtin_amdgcn_exp2f(s0b[2]), pb3 = __builtin_amdgcn_exp2f(s0b[3]);
        float pb4 = __builtin_amdgcn_exp2f(s1b[0]), pb5 = __builtin_amdgcn_exp2f(s1b[1]);
        float pb6 = __builtin_amdgcn_exp2f(s1b[2]), pb7 = __builtin_amdgcn_exp2f(s1b[3]);
        la += ((pa0+pa1)+(pa2+pa3)) + ((pa4+pa5)+(pa6+pa7));   // lane-local only
        lb += ((pb0+pb1)+(pb2+pb3)) + ((pb4+pb5)+(pb6+pb7));
        half8 pfa, pfb;
        pfa[0]=(_Float16)pa0; pfa[1]=(_Float16)pa1; pfa[2]=(_Float16)pa2; pfa[3]=(_Float16)pa3;
        pfa[4]=(_Float16)pa4; pfa[5]=(_Float16)pa5; pfa[6]=(_Float16)pa6; pfa[7]=(_Float16)pa7;
        pfb[0]=(_Float16)pb0; pfb[1]=(_Float16)pb1; pfb[2]=(_Float16)pb2; pfb[3]=(_Float16)pb3;
        pfb[4]=(_Float16)pb4; pfb[5]=(_Float16)pb5; pfb[6]=(_Float16)pb6; pfb[7]=(_Float16)pb7;
        // ---- PV: V fragments shared between both sub-tiles; no rescale ----
#pragma unroll
        for (int hc = 0; hc < 8; ++hc) {
            oa[hc] = __builtin_amdgcn_mfma_f32_16x16x32_f16(vf[hc], pfa, oa[hc], 0, 0, 0);
            ob[hc] = __builtin_amdgcn_mfma_f32_16x16x32_f16(vf[hc], pfb, ob[hc], 0, 0, 0);
        }
        // ---- rotate K buffers ----
#pragma unroll
        for (int kk = 0; kk < 4; ++kk) { kc0[kk] = kn0[kk]; kc1[kk] = kn1[kk]; }
    }

    // ---- single deferred l-reduction ----
    la += __shfl_xor(la, 16); la += __shfl_xor(la, 32);
    lb += __shfl_xor(lb, 16); lb += __shfl_xor(lb, 32);

    // ---- merge the 8 KV-split partials (straight sums) ----
    sm_l[wid][lo]      = la;
    sm_l[wid][16 + lo] = lb;
#pragma unroll
    for (int hc = 0; hc < 8; ++hc) {
        half4v va, vb;
#pragma unroll
        for (int j = 0; j < 4; ++j) { va[j] = (_Float16)oa[hc][j]; vb[j] = (_Float16)ob[hc][j]; }
        *(half4v*)(&sm_o[wid][lo][hc * 16 + 4 * hi])      = va;
        *(half4v*)(&sm_o[wid][16 + lo][hc * 16 + 4 * hi]) = vb;
    }
    __syncthreads();

#pragma unroll
    for (int qh = 0; qh < 2; ++qh) {
        const int q = qh * 16 + lo;
        float L = 0.f;
#pragma unroll
        for (int w = 0; w < 8; ++w) L += sm_l[w][q];
        const float invL = 1.f / L;
        float4v ov = {0.f, 0.f, 0.f, 0.f};
#pragma unroll
        for (int w = 0; w < 8; ++w) {
            half4v tv = *(const half4v*)(&sm_o[w][q][wid * 16 + 4 * hi]);
#pragma unroll
            for (int j = 0; j < 4; ++j) ov[j] += (float)tv[j];
        }
#pragma unroll
        for (int j = 0; j < 4; ++j) ov[j] *= invL;
        *(float4v*)(Out + ((size_t)b * S_ + q0 + q) * H_ + wid * 16 + 4 * hi) = ov;
    }
}

extern "C" void kernel_launch(void* const* d_in, const int* in_sizes, int n_in,
                              void* d_out, int out_size, void* d_ws, size_t ws_size,
                              hipStream_t stream) {
    const float* x  = (const float*)d_in[0];
    const float* Wq = (const float*)d_in[1];
    const float* bq = (const float*)d_in[2];
    const float* Wk = (const float*)d_in[3];
    const float* bk = (const float*)d_in[4];
    const float* Wv = (const float*)d_in[5];
    const float* bv = (const float*)d_in[6];
    float* out = (float*)d_out;   // reference output dtype = float32

    char* ws = (char*)d_ws;
    _Float16* WTz = (_Float16*)ws;                       //   786,432 B fragment-major
    _Float16* Qf  = (_Float16*)(ws + 786432);            // 4,194,304 B
    _Float16* Kz  = (_Float16*)(ws + 786432 + 4194304);  // 4 MB fragment-major
    _Float16* Vz  = (_Float16*)(ws + 786432 + 8388608);  // 4 MB fragment-major

    hipLaunchKernelGGL(k_cvt_w, dim3(64, 3), dim3(256), 0, stream, Wq, Wk, Wv, WTz);
    hipLaunchKernelGGL(k_proj, dim3(384), dim3(256), 0, stream,
                       x, WTz, bq, bk, bv, Qf, Kz, Vz);
    hipLaunchKernelGGL(k_attn, dim3(512), dim3(512), 0, stream, Qf, Kz, Vz, out);
}

// Round 12
// 65.471 us; speedup vs baseline: 1.6219x; 1.6219x over previous
//
#include <hip/hip_runtime.h>
#include <hip/hip_bf16.h>

#define B_ 4
#define S_ 4096
#define D_ 1024
#define H_ 128

typedef _Float16 half8 __attribute__((ext_vector_type(8)));
typedef _Float16 half4v __attribute__((ext_vector_type(4)));
typedef float float4v __attribute__((ext_vector_type(4)));

// K/V fragment-major layouts (per batch: 128 tiles x 8 frags x 64 lanes x 8 f16):
//   Kz[(b*128+tt)*4096 + (k2*2+c)*512 + lane*8 + e]
//     = K[b][tt*32 + permbase(lane&15) + 4c][k2*32 + (lane>>4)*8 + e]
//   Vz[(b*128+tt)*4096 + hc*512 + lane*8 + e]
//     = V[b][tt*32 + (lane>>4)*8 + e][hc*16 + (lane&15)]
// (permbase(l) = ((l>>2)<<3)+(l&3))  -> every k_attn fragment load is one
// contiguous 1KB burst (base + lane*16B).  [R8: 2.3x attn win]
// R11 lesson: direct fragment reads from ROW-MAJOR matrices scatter across 16
// rows (row = lane&15 in both MFMA operand slots) -> TA-serialized.  Staging
// through LDS (or pre-swizzled global) is mandatory.

// ---------------- kernel 1: W[k][n] fp32 -> WT[w][n][k] f16 ----------------
__global__ __launch_bounds__(256) void k_cvt_w(const float* __restrict__ Wq,
                                               const float* __restrict__ Wk,
                                               const float* __restrict__ Wv,
                                               _Float16* __restrict__ WT) {
    const float* W = blockIdx.y == 0 ? Wq : (blockIdx.y == 1 ? Wk : Wv);
    int idx = blockIdx.x * 256 + threadIdx.x;   // 0..131071  (grid.x = 512)
    int k = idx >> 7, n = idx & 127;
    WT[(size_t)blockIdx.y * (H_ * D_) + (size_t)n * D_ + k] = (_Float16)W[idx];
}

// ---------------- kernel 2: QKV projection GEMM (R12: fixed pipeline) ------
// R10 structure, corrected phase order.  R10's bug: loads were issued BETWEEN
// the LDS-write and the barrier -> hipcc's forced s_waitcnt vmcnt(0) before
// s_barrier drained them with zero overlap (2.3 TB/s duty cap).  R12 order:
//   barrier(a)[drain: loads have had a full MFMA phase] -> regs->LDS ->
//   barrier(b) -> issue loads(t+1) -> MFMA(t)
// so every load overlaps a whole MFMA phase before its drain point; 3 blocks/
// CU stagger the residual.  768 blocks (M-tile 64; {m,m+256,m+512} same XCD).
__global__ __launch_bounds__(256, 3) void k_proj(const float* __restrict__ X,
                                                 const _Float16* __restrict__ WT,
                                                 const float* __restrict__ bq,
                                                 const float* __restrict__ bk,
                                                 const float* __restrict__ bv,
                                                 _Float16* __restrict__ Qf,
                                                 _Float16* __restrict__ Kz,
                                                 _Float16* __restrict__ Vz) {
    __shared__ _Float16 smem[64 * 136 + 128 * 136];   // As | Bs, +8 pad each row
    _Float16* As = smem;                // [64][136]  x tile (f16)
    _Float16* Bs = smem + 64 * 136;     // [128][136] wT tile [n][k]

    const int t    = threadIdx.x;
    const int bid  = blockIdx.x;
    const int w    = bid >> 8;                     // 0=q 1=k 2=v
    const int m0   = (bid & 255) * 64;
    const int lane = t & 63, wid = t >> 6;
    const int lo   = lane & 15, hi = lane >> 4;
    const int wr   = wid >> 1, wc = wid & 1;

    const _Float16* Wt = WT + (size_t)w * (H_ * D_);

    const int xr = t >> 5, xc = (t & 31) * 4;      // X: rows xr+8i, 4 f32
    const int br = t >> 4, bc = (t & 15) * 8;      // WT: rows br+16i, 8 f16

    // prologue: tile 0 into regs
    float4v xreg[8];
    half8   wreg[8];
#pragma unroll
    for (int i2 = 0; i2 < 8; ++i2)
        xreg[i2] = *(const float4v*)(X + (size_t)(m0 + xr + i2 * 8) * D_ + xc);
#pragma unroll
    for (int i2 = 0; i2 < 8; ++i2)
        wreg[i2] = *(const half8*)(Wt + (size_t)(br + i2 * 16) * D_ + bc);

    float4v acc[2][4];
#pragma unroll
    for (int mt = 0; mt < 2; ++mt)
#pragma unroll
        for (int nt = 0; nt < 4; ++nt) acc[mt][nt] = {0.f, 0.f, 0.f, 0.f};

    for (int it = 0; it < 8; ++it) {
        __syncthreads();   // (a) prev MFMA done reading LDS; vmcnt drain here
                           //     = after a full MFMA phase of overlap
        // ---- regs -> LDS (convert X fp32->f16) ----
#pragma unroll
        for (int i2 = 0; i2 < 8; ++i2) {
            float4v xv = xreg[i2];
            half4v hv;
            hv[0] = (_Float16)xv[0]; hv[1] = (_Float16)xv[1];
            hv[2] = (_Float16)xv[2]; hv[3] = (_Float16)xv[3];
            *(half4v*)(&As[(xr + i2 * 8) * 136 + xc]) = hv;
        }
#pragma unroll
        for (int i2 = 0; i2 < 8; ++i2)
            *(half8*)(&Bs[(br + i2 * 16) * 136 + bc]) = wreg[i2];
        __syncthreads();   // (b) LDS writes visible; no loads outstanding here
        // ---- issue next tile's loads NOW: they overlap the MFMA below and
        //      are only drained at the NEXT iteration's barrier (a) ----
        if (it < 7) {
            const int k0n = (it + 1) * 128;
#pragma unroll
            for (int i2 = 0; i2 < 8; ++i2)
                xreg[i2] = *(const float4v*)(X + (size_t)(m0 + xr + i2 * 8) * D_ + k0n + xc);
#pragma unroll
            for (int i2 = 0; i2 < 8; ++i2)
                wreg[i2] = *(const half8*)(Wt + (size_t)(br + i2 * 16) * D_ + k0n + bc);
        }
        // ---- MFMA on staged tile ----
#pragma unroll
        for (int kk = 0; kk < 4; ++kk) {
            half8 af[2], bf[4];
#pragma unroll
            for (int mt = 0; mt < 2; ++mt)
                af[mt] = *(const half8*)(&As[(wr * 32 + mt * 16 + lo) * 136 + kk * 32 + hi * 8]);
#pragma unroll
            for (int nt = 0; nt < 4; ++nt)
                bf[nt] = *(const half8*)(&Bs[(wc * 64 + nt * 16 + lo) * 136 + kk * 32 + hi * 8]);
#pragma unroll
            for (int mt = 0; mt < 2; ++mt)
#pragma unroll
                for (int nt = 0; nt < 4; ++nt)
                    acc[mt][nt] = __builtin_amdgcn_mfma_f32_16x16x32_f16(
                        af[mt], bf[nt], acc[mt][nt], 0, 0, 0);
        }
    }

    // ---- epilogue: acc (+bias, *scale) -> Ct[64][136] -> burst stores ----
    const float* bias = (w == 0) ? bq : ((w == 1) ? bk : bv);
    const float scale = (w == 0) ? (0.08838834764831845f * 1.4426950408889634f) : 1.0f;
    __syncthreads();
    _Float16* Ct = smem;                           // [64][136]
#pragma unroll
    for (int mt = 0; mt < 2; ++mt)
#pragma unroll
        for (int nt = 0; nt < 4; ++nt) {
            const int col   = wc * 64 + nt * 16 + lo;
            const float bn  = bias[col];
            const int rbase = wr * 32 + mt * 16 + 4 * hi;
#pragma unroll
            for (int j = 0; j < 4; ++j)
                Ct[(rbase + j) * 136 + col] = (_Float16)((acc[mt][nt][j] + bn) * scale);
        }
    __syncthreads();

    const int bb  = m0 >> 12;                      // batch
    const int tt0 = (m0 & (S_ - 1)) >> 5;          // first 32-row KV tile

    if (w == 0) {                                  // Q: row-major bursts
        const int r = t >> 2, c0 = (t & 3) * 32;
        _Float16* dst = Qf + (size_t)(m0 + r) * H_ + c0;
        const _Float16* srcp = &Ct[r * 136 + c0];
#pragma unroll
        for (int cc = 0; cc < 4; ++cc)
            *(half8*)(dst + cc * 8) = *(const half8*)(srcp + cc * 8);
    } else if (w == 1) {                           // K: fragment-major bursts
        const int rowp = ((lo >> 2) << 3) + (lo & 3);
#pragma unroll
        for (int q = 0; q < 4; ++q) {
            const int fid = wid * 4 + q;           // 16 frags: 2 tiles x 4 k2 x 2 c
            const int ft = fid >> 3, k2 = (fid >> 1) & 3, c = fid & 1;
            const int row = ft * 32 + rowp + 4 * c;
            half8 v = *(const half8*)(&Ct[row * 136 + k2 * 32 + hi * 8]);
            *(half8*)(Kz + (size_t)(bb * 128 + tt0 + ft) * 4096 +
                      (k2 * 2 + c) * 512 + lane * 8) = v;
        }
    } else {                                       // V: transposed fragment-major
#pragma unroll
        for (int q = 0; q < 4; ++q) {
            const int fid = wid * 4 + q;           // 16 frags: 2 tiles x 8 hc
            const int ft = fid >> 3, hc = fid & 7;
            half8 v;
#pragma unroll
            for (int e = 0; e < 8; ++e)
                v[e] = Ct[(ft * 32 + hi * 8 + e) * 136 + hc * 16 + lo];
            *(half8*)(Vz + (size_t)(bb * 128 + tt0 + ft) * 4096 +
                      hc * 512 + lane * 8) = v;
        }
    }
}

// ---------------- kernel 3: causal flash attention (UNCHANGED from R8) ----
__global__ __launch_bounds__(512, 2) void k_attn(const _Float16* __restrict__ Qf,
                                                 const _Float16* __restrict__ Kz,
                                                 const _Float16* __restrict__ Vz,
                                                 float* __restrict__ Out) {
    __shared__ float    sm_l[8][32];
    __shared__ _Float16 sm_o[8][32][136];   // [wave][q][h], pad 128->136

    const int t    = threadIdx.x;
    const int lane = t & 63, wid = t >> 6;
    const int lo = lane & 15, hi = lane >> 4;

    const int i   = blockIdx.x;            // 0..511
    const int b   = (i >> 1) & 3;          // batch -> XCD pair {2b, 2b+1}
    const int qtr = ((i >> 3) << 1) | (i & 1);          // 0..127
    const int qt  = (qtr < 64) ? qtr : (191 - qtr);     // zigzag: i & i+256 complement
    const int q0  = qt << 5;               // 32 queries: q0..q0+31

    const _Float16* Qb = Qf + (size_t)b * (S_ * H_);
    const _Float16* Kb = Kz + (size_t)b * 524288;   // 128 tiles * 4096
    const _Float16* Vb = Vz + (size_t)b * 524288;

    half8 qfa[4], qfb[4];
#pragma unroll
    for (int kk = 0; kk < 4; ++kk) {
        qfa[kk] = *(const half8*)(Qb + (size_t)(q0 + lo) * H_ + kk * 32 + hi * 8);
        qfb[kk] = *(const half8*)(Qb + (size_t)(q0 + 16 + lo) * H_ + kk * 32 + hi * 8);
    }

    float4v oa[8], ob[8];
#pragma unroll
    for (int hc = 0; hc < 8; ++hc) { oa[hc] = {0.f,0.f,0.f,0.f}; ob[hc] = {0.f,0.f,0.f,0.f}; }
    float la = 0.f, lb = 0.f;   // LANE-LOCAL partial row-sums (reduced after loop)

    const int lane8 = lane * 8;
    const int ntiles = qt + 1;             // keys 0..q0+31, 32/tile

    // prime the K double-buffer with this wave's first tile
    half8 kc0[4], kc1[4];
    if (wid < ntiles) {
        const _Float16* Kt = Kb + (size_t)wid * 4096 + lane8;
#pragma unroll
        for (int kk = 0; kk < 4; ++kk) {
            kc0[kk] = *(const half8*)(Kt + (kk * 2    ) * 512);
            kc1[kk] = *(const half8*)(Kt + (kk * 2 + 1) * 512);
        }
    }

    for (int tt = wid; tt < ntiles; tt += 8) {
        // ---- V loads issued first: latency hides under QK + exp ----
        const _Float16* Vt = Vb + (size_t)tt * 4096 + lane8;
        half8 vf[8];
#pragma unroll
        for (int hc = 0; hc < 8; ++hc)
            vf[hc] = *(const half8*)(Vt + hc * 512);
        // ---- prefetch next K tile (clamped re-load of current on last iter) ----
        const int tn = (tt + 8 < ntiles) ? (tt + 8) : tt;
        half8 kn0[4], kn1[4];
        {
            const _Float16* Ktn = Kb + (size_t)tn * 4096 + lane8;
#pragma unroll
            for (int kk = 0; kk < 4; ++kk) {
                kn0[kk] = *(const half8*)(Ktn + (kk * 2    ) * 512);
                kn1[kk] = *(const half8*)(Ktn + (kk * 2 + 1) * 512);
            }
        }
        // ---- QK^T on the current (already-resident) K fragments ----
        float4v s0a = {0.f,0.f,0.f,0.f}, s1a = {0.f,0.f,0.f,0.f};
        float4v s0b = {0.f,0.f,0.f,0.f}, s1b = {0.f,0.f,0.f,0.f};
#pragma unroll
        for (int kk = 0; kk < 4; ++kk) {
            s0a = __builtin_amdgcn_mfma_f32_16x16x32_f16(kc0[kk], qfa[kk], s0a, 0, 0, 0);
            s0b = __builtin_amdgcn_mfma_f32_16x16x32_f16(kc0[kk], qfb[kk], s0b, 0, 0, 0);
            s1a = __builtin_amdgcn_mfma_f32_16x16x32_f16(kc1[kk], qfa[kk], s1a, 0, 0, 0);
            s1b = __builtin_amdgcn_mfma_f32_16x16x32_f16(kc1[kk], qfb[kk], s1b, 0, 0, 0);
        }
        // s0x[j] = S[q][k0+8hi+j], s1x[j] = S[q][k0+8hi+4+j]
        if (tt == qt) {   // diagonal tile: only place masking is needed
#pragma unroll
            for (int j = 0; j < 4; ++j) {
                const int c0 = 8 * hi + j, c1 = 8 * hi + 4 + j;
                if (c0 > lo)      s0a[j] = -INFINITY;
                if (c1 > lo)      s1a[j] = -INFINITY;
                if (c0 > 16 + lo) s0b[j] = -INFINITY;
                if (c1 > 16 + lo) s1b[j] = -INFINITY;
            }
        }
        // ---- no-max softmax, exp2 direct (exp2(-inf) = 0 handles masks) ----
        float pa0 = __builtin_amdgcn_exp2f(s0a[0]), pa1 = __builtin_amdgcn_exp2f(s0a[1]);
        float pa2 = __builtin_amdgcn_exp2f(s0a[2]), pa3 = __builtin_amdgcn_exp2f(s0a[3]);
        float pa4 = __builtin_amdgcn_exp2f(s1a[0]), pa5 = __builtin_amdgcn_exp2f(s1a[1]);
        float pa6 = __builtin_amdgcn_exp2f(s1a[2]), pa7 = __builtin_amdgcn_exp2f(s1a[3]);
        float pb0 = __builtin_amdgcn_exp2f(s0b[0]), pb1 = __builtin_amdgcn_exp2f(s0b[1]);
        float pb2 = __builtin_amdgcn_exp2f(s0b[2]), pb3 = __builtin_amdgcn_exp2f(s0b[3]);
        float pb4 = __builtin_amdgcn_exp2f(s1b[0]), pb5 = __builtin_amdgcn_exp2f(s1b[1]);
        float pb6 = __builtin_amdgcn_exp2f(s1b[2]), pb7 = __builtin_amdgcn_exp2f(s1b[3]);
        la += ((pa0+pa1)+(pa2+pa3)) + ((pa4+pa5)+(pa6+pa7));   // lane-local only
        lb += ((pb0+pb1)+(pb2+pb3)) + ((pb4+pb5)+(pb6+pb7));
        half8 pfa, pfb;
        pfa[0]=(_Float16)pa0; pfa[1]=(_Float16)pa1; pfa[2]=(_Float16)pa2; pfa[3]=(_Float16)pa3;
        pfa[4]=(_Float16)pa4; pfa[5]=(_Float16)pa5; pfa[6]=(_Float16)pa6; pfa[7]=(_Float16)pa7;
        pfb[0]=(_Float16)pb0; pfb[1]=(_Float16)pb1; pfb[2]=(_Float16)pb2; pfb[3]=(_Float16)pb3;
        pfb[4]=(_Float16)pb4; pfb[5]=(_Float16)pb5; pfb[6]=(_Float16)pb6; pfb[7]=(_Float16)pb7;
        // ---- PV: V fragments shared between both sub-tiles; no rescale ----
#pragma unroll
        for (int hc = 0; hc < 8; ++hc) {
            oa[hc] = __builtin_amdgcn_mfma_f32_16x16x32_f16(vf[hc], pfa, oa[hc], 0, 0, 0);
            ob[hc] = __builtin_amdgcn_mfma_f32_16x16x32_f16(vf[hc], pfb, ob[hc], 0, 0, 0);
        }
        // ---- rotate K buffers ----
#pragma unroll
        for (int kk = 0; kk < 4; ++kk) { kc0[kk] = kn0[kk]; kc1[kk] = kn1[kk]; }
    }

    // ---- single deferred l-reduction ----
    la += __shfl_xor(la, 16); la += __shfl_xor(la, 32);
    lb += __shfl_xor(lb, 16); lb += __shfl_xor(lb, 32);

    // ---- merge the 8 KV-split partials (straight sums) ----
    sm_l[wid][lo]      = la;
    sm_l[wid][16 + lo] = lb;
#pragma unroll
    for (int hc = 0; hc < 8; ++hc) {
        half4v va, vb;
#pragma unroll
        for (int j = 0; j < 4; ++j) { va[j] = (_Float16)oa[hc][j]; vb[j] = (_Float16)ob[hc][j]; }
        *(half4v*)(&sm_o[wid][lo][hc * 16 + 4 * hi])      = va;
        *(half4v*)(&sm_o[wid][16 + lo][hc * 16 + 4 * hi]) = vb;
    }
    __syncthreads();

#pragma unroll
    for (int qh = 0; qh < 2; ++qh) {
        const int q = qh * 16 + lo;
        float L = 0.f;
#pragma unroll
        for (int w = 0; w < 8; ++w) L += sm_l[w][q];
        const float invL = 1.f / L;
        float4v ov = {0.f, 0.f, 0.f, 0.f};
#pragma unroll
        for (int w = 0; w < 8; ++w) {
            half4v tv = *(const half4v*)(&sm_o[w][q][wid * 16 + 4 * hi]);
#pragma unroll
            for (int j = 0; j < 4; ++j) ov[j] += (float)tv[j];
        }
#pragma unroll
        for (int j = 0; j < 4; ++j) ov[j] *= invL;
        *(float4v*)(Out + ((size_t)b * S_ + q0 + q) * H_ + wid * 16 + 4 * hi) = ov;
    }
}

extern "C" void kernel_launch(void* const* d_in, const int* in_sizes, int n_in,
                              void* d_out, int out_size, void* d_ws, size_t ws_size,
                              hipStream_t stream) {
    const float* x  = (const float*)d_in[0];
    const float* Wq = (const float*)d_in[1];
    const float* bq = (const float*)d_in[2];
    const float* Wk = (const float*)d_in[3];
    const float* bk = (const float*)d_in[4];
    const float* Wv = (const float*)d_in[5];
    const float* bv = (const float*)d_in[6];
    float* out = (float*)d_out;   // reference output dtype = float32

    char* ws = (char*)d_ws;
    _Float16* WT = (_Float16*)ws;                       //   786,432 B
    _Float16* Qf = (_Float16*)(ws + 786432);            // 4,194,304 B
    _Float16* Kz = (_Float16*)(ws + 786432 + 4194304);  // 4 MB fragment-major
    _Float16* Vz = (_Float16*)(ws + 786432 + 8388608);  // 4 MB fragment-major

    hipLaunchKernelGGL(k_cvt_w, dim3(512, 3), dim3(256), 0, stream, Wq, Wk, Wv, WT);
    hipLaunchKernelGGL(k_proj, dim3(768), dim3(256), 0, stream,
                       x, WT, bq, bk, bv, Qf, Kz, Vz);
    hipLaunchKernelGGL(k_attn, dim3(512), dim3(512), 0, stream, Qf, Kz, Vz, out);
}